// Round 10
// baseline (268.268 us; speedup 1.0000x reference)
//
#include <hip/hip_runtime.h>

typedef unsigned short u16;
typedef short short8 __attribute__((ext_vector_type(8)));
typedef float f32x4 __attribute__((ext_vector_type(4)));
typedef unsigned long long u64;

// ---- new-path ws layout (bytes) ----
#define WS_K_OFF    33554432ULL
#define WS_PTRI     67108864ULL
#define WS_PART     104857600ULL      // ragged f32 partials, 589824 B
#define WS_NEED     105447424ULL

__device__ __forceinline__ u16 f2bf(float f) {
    union { float f; unsigned u; } c; c.f = f;
    unsigned r = c.u + 0x7fffu + ((c.u >> 16) & 1u);
    return (u16)(r >> 16);
}
__device__ __forceinline__ float bf2f(u16 h) {
    union { unsigned u; float f; } c; c.u = ((unsigned)h) << 16; return c.f;
}
__device__ __forceinline__ void gll16(const u16* g, u16* l) {
    __builtin_amdgcn_global_load_lds(
        (const __attribute__((address_space(1))) void*)g,
        (__attribute__((address_space(3))) void*)l, 16, 0, 0);
}

// ---------------------------------------------------------------------------
// r7/r8 deep-pipe 256x256 NT-GEMM mainloop (REVERTED to best-measured: BK=32,
// 8 waves 2Mx4N, quad-buffer 128 KiB, stage-3-ahead, reg-double-buffered A).
// Phase-split variants (r5, r9) both regressed — class closed.
// ---------------------------------------------------------------------------
template<int AMODE>
__device__ __forceinline__ void gemm_pipe(
    const u16* __restrict__ A, int lda,
    const u16* __restrict__ B, int ldb,
    int m0, int n0, int nk, u16* lds, f32x4 acc[8][4])
{
    const int tid  = threadIdx.x;
    const int lane = tid & 63;
    const int w    = tid >> 6;
    const int wm   = w >> 2, wn = w & 3;
    const int kg   = lane >> 4, l15 = lane & 15;
    const int r0   = w * 32 + (lane >> 2);
    const int s0   = (lane & 3) ^ ((r0 >> 1) & 3);

    const int ldA = AMODE ? 256 : lda;
    const u16* Ar0 = A + (size_t)(m0 + r0) * ldA + s0 * 8;
    const u16* Ar1 = Ar0 + 16 * ldA;
    const u16* Br0 = B + (size_t)(n0 + r0) * ldb + s0 * 8;
    const u16* Br1 = Br0 + 16 * ldb;

    auto aoff = [&](int t) -> int {
        return AMODE ? ((t >> 3) * 65536 + (t & 7) * 32) : t * 32;
    };
    auto STAGE = [&](int t) {
        const int ao = aoff(t), bo = t * 32, buf = (t & 3) * 16384;
        u16* dA = lds + buf + w * 1024;
        u16* dB = lds + buf + 8192 + w * 1024;
        gll16(Ar0 + ao, dA);
        gll16(Ar1 + ao, dA + 512);
        gll16(Br0 + bo, dB);
        gll16(Br1 + bo, dB + 512);
    };
    auto LDA8 = [&](short8* fa, int t) {
        const u16* h = lds + (t & 3) * 16384 + wm * 4096;
        #pragma unroll
        for (int mt = 0; mt < 8; ++mt) {
            const int row = mt * 16 + l15;
            fa[mt] = *reinterpret_cast<const short8*>(
                h + row * 32 + ((kg ^ ((row >> 1) & 3)) << 3));
        }
    };
    auto LDB4 = [&](short8* fb, int t) {
        const u16* h = lds + (t & 3) * 16384 + 8192 + wn * 2048;
        #pragma unroll
        for (int nt = 0; nt < 4; ++nt) {
            const int row = nt * 16 + l15;
            fb[nt] = *reinterpret_cast<const short8*>(
                h + row * 32 + ((kg ^ ((row >> 1) & 3)) << 3));
        }
    };
    auto MFMA32 = [&](short8* fa, short8* fb) {
        __builtin_amdgcn_s_setprio(1);
        #pragma unroll
        for (int mt = 0; mt < 8; ++mt)
            #pragma unroll
            for (int nt = 0; nt < 4; ++nt)
                acc[mt][nt] = __builtin_amdgcn_mfma_f32_16x16x32_bf16(
                    fa[mt], fb[nt], acc[mt][nt], 0, 0, 0);
        __builtin_amdgcn_s_setprio(0);
    };

    STAGE(0); STAGE(1); STAGE(2);
    asm volatile("s_waitcnt vmcnt(4)" ::: "memory");   // tiles 0,1 landed
    __builtin_amdgcn_s_barrier();

    short8 faA[8], faB[8], fb[4];
    LDA8(faA, 0);

    for (int t = 0; t < nk; t += 2) {
        LDB4(fb, t);
        LDA8(faB, t + 1);
        if (t + 3 < nk) STAGE(t + 3);
        MFMA32(faA, fb);
        if (t + 3 < nk) asm volatile("s_waitcnt vmcnt(4)" ::: "memory");
        else            asm volatile("s_waitcnt vmcnt(0)" ::: "memory");
        __builtin_amdgcn_s_barrier();

        LDB4(fb, t + 1);
        if (t + 2 < nk) LDA8(faA, t + 2);
        if (t + 4 < nk) STAGE(t + 4);
        MFMA32(faB, fb);
        if (t + 4 < nk) asm volatile("s_waitcnt vmcnt(4)" ::: "memory");
        else            asm volatile("s_waitcnt vmcnt(0)" ::: "memory");
        __builtin_amdgcn_s_barrier();
    }
}

// ---------------------------------------------------------------------------
// 0) cast x and Wq/Wk/Wv to bf16 into d_out: xb[16M] then Wb[3][1M]
// ---------------------------------------------------------------------------
__global__ __launch_bounds__(256) void cvt_bf16(
    const float* __restrict__ x,
    const float* __restrict__ Wq,
    const float* __restrict__ Wk,
    const float* __restrict__ Wv,
    u16* __restrict__ dst)
{
    const size_t e = ((size_t)blockIdx.x * 256 + threadIdx.x) * 8;
    const float* src;
    if (e < (size_t)16777216) {
        src = x + e;
    } else {
        size_t j = e - 16777216;
        int z = (int)(j >> 20);
        const float* Wz = (z == 0) ? Wq : (z == 1) ? Wk : Wv;
        src = Wz + (j & 1048575);
    }
    float4 a = *reinterpret_cast<const float4*>(src);
    float4 b = *reinterpret_cast<const float4*>(src + 4);
    short8 v;
    v[0] = (short)f2bf(a.x); v[1] = (short)f2bf(a.y);
    v[2] = (short)f2bf(a.z); v[3] = (short)f2bf(a.w);
    v[4] = (short)f2bf(b.x); v[5] = (short)f2bf(b.y);
    v[6] = (short)f2bf(b.z); v[7] = (short)f2bf(b.w);
    *reinterpret_cast<short8*>(dst + e) = v;
}

// ---------------------------------------------------------------------------
// 1) projection (Q,K new path; Q,K,V^T-scatter old path).
// ---------------------------------------------------------------------------
__global__ __launch_bounds__(512, 2) void qkv_pipe(
    const u16* __restrict__ xb, const u16* __restrict__ Wb,
    u16* __restrict__ Qo, u16* __restrict__ Ko, u16* __restrict__ VTo, int zbase)
{
    __shared__ u16 L[65536];
    const int tid = threadIdx.x, lane = tid & 63, w = tid >> 6;
    const int wm = w >> 2, wn = w & 3, kg = lane >> 4, l15 = lane & 15;
    const int m0 = blockIdx.x * 256, n0 = blockIdx.y * 256;
    const int z = blockIdx.z + zbase;

    const f32x4 z4 = {0.f, 0.f, 0.f, 0.f};
    f32x4 acc[8][4];
    #pragma unroll
    for (int i = 0; i < 8; ++i)
        #pragma unroll
        for (int j = 0; j < 4; ++j) acc[i][j] = z4;

    gemm_pipe<0>(xb, 1024, Wb + (size_t)z * 1048576, 1024, m0, n0, 32, L, acc);

    if (z < 2) {
        u16* O = (z == 0) ? Qo : Ko;
        #pragma unroll
        for (int mt = 0; mt < 8; ++mt) {
            const int row0 = m0 + wm * 128 + mt * 16 + kg * 4;
            #pragma unroll
            for (int nt = 0; nt < 4; ++nt) {
                const int col = n0 + wn * 64 + nt * 16 + l15;
                #pragma unroll
                for (int r = 0; r < 4; ++r)
                    O[(size_t)(row0 + r) * 1024 + col] = f2bf(acc[mt][nt][r]);
            }
        }
    } else {
        #pragma unroll
        for (int mt = 0; mt < 8; ++mt) {
            const int row0 = m0 + wm * 128 + mt * 16 + kg * 4;
            #pragma unroll
            for (int nt = 0; nt < 4; ++nt) {
                const int col = n0 + wn * 64 + nt * 16 + l15;   // h
                #pragma unroll
                for (int r = 0; r < 4; ++r) {
                    const int rr = row0 + r;
                    VTo[((size_t)(rr >> 11) * 1024 + col) * 2048 + (rr & 2047)] = f2bf(acc[mt][nt][r]);
                }
            }
        }
    }
}

// ---------------------------------------------------------------------------
// Shared triple-buffer 256x128 NT-GEMM body (unchanged from r8): 8 waves
// 4Mx2N, 3 bufs x 24 KiB = 72 KiB -> 2 blocks/CU, stage-2-ahead, vmcnt(3).
// ---------------------------------------------------------------------------
template<int AMODE>
__device__ __forceinline__ void gemm_tri128(
    const u16* __restrict__ A, int lda,
    const u16* __restrict__ B, int ldb, int nk, u16* L, f32x4 acc[4][4])
{
    const int tid = threadIdx.x, lane = tid & 63, w = tid >> 6;
    const int wm = w >> 1, wn = w & 1, kg = lane >> 4, l15 = lane & 15;

    const int rA = w * 32 + (lane >> 2);
    const int sA = (lane & 3) ^ ((rA >> 1) & 3);
    const int rB = w * 16 + (lane >> 2);
    const int sB = (lane & 3) ^ ((rB >> 1) & 3);
    const int ldA = AMODE ? 256 : lda;
    const u16* Ar0 = A + (size_t)rA * ldA + sA * 8;
    const u16* Ar1 = Ar0 + 16 * ldA;
    const u16* Br0 = B + (size_t)rB * ldb + sB * 8;

    auto aoff = [&](int t) -> int {
        return AMODE ? ((t >> 3) * 65536 + (t & 7) * 32) : t * 32;
    };
    auto STAGE = [&](int t) {
        u16* d = L + (t % 3) * 12288;
        gll16(Ar0 + aoff(t), d + w * 1024);
        gll16(Ar1 + aoff(t), d + w * 1024 + 512);
        gll16(Br0 + t * 32,  d + 8192 + w * 512);
    };
    auto LDA4 = [&](short8* fa, int t) {
        const u16* h = L + (t % 3) * 12288;
        #pragma unroll
        for (int mt = 0; mt < 4; ++mt) {
            const int row = wm * 64 + mt * 16 + l15;
            fa[mt] = *reinterpret_cast<const short8*>(
                h + row * 32 + ((kg ^ ((row >> 1) & 3)) << 3));
        }
    };
    auto LDB4 = [&](short8* fb, int t) {
        const u16* h = L + (t % 3) * 12288 + 8192;
        #pragma unroll
        for (int nt = 0; nt < 4; ++nt) {
            const int row = wn * 64 + nt * 16 + l15;
            fb[nt] = *reinterpret_cast<const short8*>(
                h + row * 32 + ((kg ^ ((row >> 1) & 3)) << 3));
        }
    };

    STAGE(0); STAGE(1);
    asm volatile("s_waitcnt vmcnt(3)" ::: "memory");   // tile 0 landed
    __builtin_amdgcn_s_barrier();

    short8 fa[4], fb[4];
    for (int t = 0; t < nk; ++t) {
        LDA4(fa, t);
        LDB4(fb, t);
        if (t + 2 < nk) STAGE(t + 2);
        __builtin_amdgcn_s_setprio(1);
        #pragma unroll
        for (int mt = 0; mt < 4; ++mt)
            #pragma unroll
            for (int nt = 0; nt < 4; ++nt)
                acc[mt][nt] = __builtin_amdgcn_mfma_f32_16x16x32_bf16(
                    fa[mt], fb[nt], acc[mt][nt], 0, 0, 0);
        __builtin_amdgcn_s_setprio(0);
        if (t + 2 < nk) asm volatile("s_waitcnt vmcnt(3)" ::: "memory");
        else            asm volatile("s_waitcnt vmcnt(0)" ::: "memory");
        __builtin_amdgcn_s_barrier();
    }
}

// ---------------------------------------------------------------------------
// 1c) NEW: vproj128 — V^T projection with LDS-transposed COALESCED writes.
// 512 jobs (256t x 128h tiles), 2 blocks/CU = exactly 1 round. Epilogue:
// acc -> LDS[h][t] ([128][264] u16, packed 8B ds_writes, 2-4 way conflicts
// only), then 16B/lane contiguous global stores of V^T rows.
// ---------------------------------------------------------------------------
__global__ __launch_bounds__(512, 4) void vproj128(
    const u16* __restrict__ xb, const u16* __restrict__ Wb,
    u16* __restrict__ VTo)
{
    __shared__ u16 L[36864];    // 72 KiB; transpose area uses [128][264]
    const int i = blockIdx.x;
    const int m0 = (i >> 3) * 256;       // t-range base
    const int n0 = (i & 7) * 128;        // h-range base

    const int tid = threadIdx.x, lane = tid & 63, w = tid >> 6;
    const int wm = w >> 1, wn = w & 1, kg = lane >> 4, l15 = lane & 15;

    const f32x4 z4 = {0.f, 0.f, 0.f, 0.f};
    f32x4 acc[4][4];
    #pragma unroll
    for (int a_ = 0; a_ < 4; ++a_)
        #pragma unroll
        for (int j = 0; j < 4; ++j) acc[a_][j] = z4;

    gemm_tri128<0>(xb + (size_t)m0 * 1024, 1024,
                   Wb + (size_t)2 * 1048576 + (size_t)n0 * 1024, 1024,
                   32, L, acc);
    // mainloop ends vmcnt(0)+barrier: LDS quiescent, safe to reuse

    #pragma unroll
    for (int mt = 0; mt < 4; ++mt) {
        const int tb = wm * 64 + mt * 16 + kg * 4;   // multiple of 4
        #pragma unroll
        for (int nt = 0; nt < 4; ++nt) {
            const int h = wn * 64 + nt * 16 + l15;
            u64 pk = (u64)f2bf(acc[mt][nt][0])
                   | ((u64)f2bf(acc[mt][nt][1]) << 16)
                   | ((u64)f2bf(acc[mt][nt][2]) << 32)
                   | ((u64)f2bf(acc[mt][nt][3]) << 48);
            *reinterpret_cast<u64*>(&L[h * 264 + tb]) = pk;   // 8B aligned
        }
    }
    __syncthreads();

    const int b    = m0 >> 11;
    const int mloc = m0 & 2047;
    const int t8   = (tid & 31) * 8;
    const int hh   = tid >> 5;           // 0..15
    #pragma unroll
    for (int p = 0; p < 8; ++p) {
        const int h = p * 16 + hh;
        short8 v = *reinterpret_cast<const short8*>(&L[h * 264 + t8]);
        *reinterpret_cast<short8*>(
            &VTo[((size_t)b * 1024 + n0 + h) * 2048 + mloc + t8]) = v;
    }
}

// ---------------------------------------------------------------------------
// 2a) NEW: sp128 (unchanged from r8)
// ---------------------------------------------------------------------------
__global__ __launch_bounds__(512, 4) void sp128(
    const u16* __restrict__ Q, const u16* __restrict__ K,
    u16* __restrict__ Ptri, float* __restrict__ part)
{
    __shared__ u16 L[36864];
    int jj = blockIdx.x;
    const int b = jj / 72;
    int r = jj - b * 72;
    int qb = 0;
    while (r >= 2 * qb + 2) { r -= 2 * qb + 2; ++qb; }
    const int kb = r;

    const int tid = threadIdx.x, lane = tid & 63, w = tid >> 6;
    const int wm = w >> 1, wn = w & 1, kg = lane >> 4, l15 = lane & 15;

    const f32x4 z4 = {0.f, 0.f, 0.f, 0.f};
    f32x4 acc[4][4];
    #pragma unroll
    for (int a_ = 0; a_ < 4; ++a_)
        #pragma unroll
        for (int j = 0; j < 4; ++j) acc[a_][j] = z4;

    gemm_tri128<0>(Q + (size_t)(b * 2048 + qb * 256) * 1024, 1024,
                   K + (size_t)(b * 2048 + kb * 128) * 1024, 1024,
                   32, L, acc);

    u16* Pt = Ptri + ((size_t)b * 36 + (qb * (qb + 1)) / 2 + (kb >> 1)) * 65536
                   + (kb & 1) * 128;
    float* psum = (float*)L;
    #pragma unroll
    for (int mt = 0; mt < 4; ++mt) {
        #pragma unroll
        for (int rr = 0; rr < 4; ++rr) {
            const int lt = wm * 64 + mt * 16 + kg * 4 + rr;
            const int gt = qb * 256 + lt;
            float ps = 0.f;
            #pragma unroll
            for (int nt = 0; nt < 4; ++nt) {
                const int lcol = wn * 64 + nt * 16 + l15;
                const int gs = kb * 128 + lcol;
                const float p = (gs <= gt) ? __expf(acc[mt][nt][rr] * 0.03125f) : 0.f;
                ps += p;
                Pt[(size_t)lt * 256 + lcol] = f2bf(p);
            }
            #pragma unroll
            for (int d = 1; d < 16; d <<= 1) ps += __shfl_xor(ps, d, 64);
            if (l15 == 0) psum[lt * 2 + wn] = ps;
        }
    }
    __syncthreads();
    if (tid < 256) {
        const float s = psum[tid * 2] + psum[tid * 2 + 1];
        part[(size_t)b * 18432 + (qb * qb + qb) * 256 + tid * (2 * qb + 2) + kb] = s;
    }
}

// 2b) OLD: full-square P in d_out (fallback path)
__global__ __launch_bounds__(512, 2) void sp_old(
    const u16* __restrict__ Q, const u16* __restrict__ K, u16* __restrict__ P)
{
    const int qb = blockIdx.x, kb = blockIdx.y, b = blockIdx.z;
    if (kb > qb) return;
    __shared__ u16 L[65536];
    const int tid = threadIdx.x, lane = tid & 63, w = tid >> 6;
    const int wm = w >> 2, wn = w & 3, kg = lane >> 4, l15 = lane & 15;

    const f32x4 z4 = {0.f, 0.f, 0.f, 0.f};
    f32x4 acc[8][4];
    #pragma unroll
    for (int i = 0; i < 8; ++i)
        #pragma unroll
        for (int j = 0; j < 4; ++j) acc[i][j] = z4;

    gemm_pipe<0>(Q, 1024, K, 1024, b * 2048 + qb * 256, b * 2048 + kb * 256, 32, L, acc);

    u16* Pb = P + (size_t)b * 2048 * 2048;
    #pragma unroll
    for (int mt = 0; mt < 8; ++mt) {
        const int trow0 = qb * 256 + wm * 128 + mt * 16 + kg * 4;
        #pragma unroll
        for (int nt = 0; nt < 4; ++nt) {
            const int scol = kb * 256 + wn * 64 + nt * 16 + l15;
            #pragma unroll
            for (int r = 0; r < 4; ++r) {
                const int trow = trow0 + r;
                const float p = (scol <= trow) ? __expf(acc[mt][nt][r] * 0.03125f) : 0.f;
                Pb[(size_t)trow * 2048 + scol] = f2bf(p);
            }
        }
    }
}

// ---------------------------------------------------------------------------
// 4a) NEW: pv128 (unchanged from r8)
// ---------------------------------------------------------------------------
__global__ __launch_bounds__(512, 4) void pv128(
    const u16* __restrict__ Ptri, const u16* __restrict__ VT,
    const float* __restrict__ part, float* __restrict__ out)
{
    __shared__ u16 L[36864];
    const int i = blockIdx.x;
    const int c = i >> 7;
    const int j = (i >> 1) & 63;
    const int s = i & 1;
    const int q  = s ? c : 7 - c;
    const int b  = j >> 3;
    const int nb = j & 7;
    const int nk = (q + 1) * 8;

    const int tid = threadIdx.x, lane = tid & 63, w = tid >> 6;
    const int wm = w >> 1, wn = w & 1, kg = lane >> 4, l15 = lane & 15;

    const f32x4 z4 = {0.f, 0.f, 0.f, 0.f};
    f32x4 acc[4][4];
    #pragma unroll
    for (int a_ = 0; a_ < 4; ++a_)
        #pragma unroll
        for (int jx = 0; jx < 4; ++jx) acc[a_][jx] = z4;

    gemm_tri128<1>(Ptri + ((size_t)b * 36 + (q * (q + 1)) / 2) * 65536, 256,
                   VT + ((size_t)b * 1024 + nb * 128) * 2048, 2048,
                   nk, L, acc);

    float* Lf = (float*)L;
    if (tid < 256) {
        const int nkb = 2 * q + 2;
        const float* pp = part + (size_t)b * 18432 + (q * q + q) * 256 + tid * nkb;
        float sum = 0.f;
        for (int kb = 0; kb < nkb; ++kb) sum += pp[kb];
        Lf[tid] = 1.f / sum;
    }
    __syncthreads();

    #pragma unroll
    for (int mt = 0; mt < 4; ++mt) {
        const int lt0 = wm * 64 + mt * 16 + kg * 4;
        const size_t grow0 = (size_t)b * 2048 + q * 256 + lt0;
        float rs[4];
        #pragma unroll
        for (int r = 0; r < 4; ++r) rs[r] = Lf[lt0 + r];
        #pragma unroll
        for (int nt = 0; nt < 4; ++nt) {
            const int col = nb * 128 + wn * 64 + nt * 16 + l15;
            #pragma unroll
            for (int r = 0; r < 4; ++r)
                out[(grow0 + r) * 1024 + col] = acc[mt][nt][r] * rs[r];
        }
    }
}

// 4b) OLD: O = P * V^T (unnormalized f32) -> Of in ws
__global__ __launch_bounds__(512, 2) void pv_old(
    const u16* __restrict__ P, const u16* __restrict__ VT, float* __restrict__ Of)
{
    const int b = blockIdx.x >> 3, qblk = blockIdx.x & 7;
    const int nb = blockIdx.y;
    const int nk = (qblk + 1) * 8;
    __shared__ u16 L[65536];
    const int tid = threadIdx.x, lane = tid & 63, w = tid >> 6;
    const int wm = w >> 2, wn = w & 3, kg = lane >> 4, l15 = lane & 15;

    const f32x4 z4 = {0.f, 0.f, 0.f, 0.f};
    f32x4 acc[8][4];
    #pragma unroll
    for (int i = 0; i < 8; ++i)
        #pragma unroll
        for (int j = 0; j < 4; ++j) acc[i][j] = z4;

    gemm_pipe<0>(P + (size_t)b * 2048 * 2048, 2048,
                 VT + (size_t)b * 1024 * 2048, 2048,
                 qblk * 256, nb * 256, nk, L, acc);

    #pragma unroll
    for (int mt = 0; mt < 8; ++mt) {
        const int trow0 = qblk * 256 + wm * 128 + mt * 16 + kg * 4;
        #pragma unroll
        for (int nt = 0; nt < 4; ++nt) {
            const int col = nb * 256 + wn * 64 + nt * 16 + l15;
            #pragma unroll
            for (int r = 0; r < 4; ++r)
                Of[((size_t)b * 2048 + trow0 + r) * 1024 + col] = acc[mt][nt][r];
        }
    }
}

// 5) OLD: per row l = sum(P row); out = Of / l
__global__ __launch_bounds__(256) void finalize(
    const u16* __restrict__ P, const float* __restrict__ Of, float* __restrict__ out)
{
    const int row = blockIdx.x;
    const int tid = threadIdx.x;
    const int b = row >> 11, t = row & 2047;
    const int len = ((t >> 8) + 1) * 256;
    const u16* prow = P + ((size_t)b * 2048 + t) * 2048;

    float s = 0.f;
    const int i = tid * 8;
    if (i < len) {
        short8 v = *reinterpret_cast<const short8*>(prow + i);
        #pragma unroll
        for (int j = 0; j < 8; ++j) s += bf2f((u16)v[j]);
    }
    #pragma unroll
    for (int d = 1; d < 64; d <<= 1) s += __shfl_xor(s, d, 64);

    __shared__ float red[4];
    if ((tid & 63) == 0) red[tid >> 6] = s;
    __syncthreads();
    const float rinv = 1.f / (red[0] + red[1] + red[2] + red[3]);

    const size_t o = (size_t)row * 1024 + tid * 4;
    f32x4 v = *reinterpret_cast<const f32x4*>(Of + o);
    v[0] *= rinv; v[1] *= rinv; v[2] *= rinv; v[3] *= rinv;
    *reinterpret_cast<f32x4*>(out + o) = v;
}

extern "C" void kernel_launch(void* const* d_in, const int* in_sizes, int n_in,
                              void* d_out, int out_size, void* d_ws, size_t ws_size,
                              hipStream_t stream) {
    const float* x  = (const float*)d_in[0];
    const float* Wq = (const float*)d_in[1];
    const float* Wk = (const float*)d_in[2];
    const float* Wv = (const float*)d_in[3];

    // d_out overlays: phase A = xb[16M]+Wb[3M] bf16; final = out f32
    u16* xb = (u16*)d_out;
    u16* Wb = xb + (size_t)16777216;

    cvt_bf16<<<dim3(9728), 256, 0, stream>>>(x, Wq, Wk, Wv, xb);

    if (ws_size >= WS_NEED) {
        // NEW: ws = Q | K | P_tri | ragged partials ; VT overwrites Q after sp
        u16*   Qb   = (u16*)d_ws;
        u16*   Kb   = (u16*)((char*)d_ws + WS_K_OFF);
        u16*   Pt   = (u16*)((char*)d_ws + WS_PTRI);
        float* part = (float*)((char*)d_ws + WS_PART);
        u16*   VTb  = Qb;   // Q dead after sp128

        qkv_pipe<<<dim3(64, 4, 2), 512, 0, stream>>>(xb, Wb, Qb, Kb, Qb, 0);
        sp128<<<dim3(576), 512, 0, stream>>>(Qb, Kb, Pt, part);
        vproj128<<<dim3(512), 512, 0, stream>>>(xb, Wb, VTb);
        pv128<<<dim3(512), 512, 0, stream>>>(Pt, VTb, part, (float*)d_out);
    } else {
        // OLD (round-3 dataflow): ws = Q | K | VT ; P in d_out; Of over Q/K
        u16* Qb  = (u16*)d_ws;
        u16* Kb  = Qb + (size_t)16384 * 1024;
        u16* VTb = Kb + (size_t)16384 * 1024;
        float* Of = (float*)d_ws;
        u16* Pb = (u16*)d_out;

        qkv_pipe<<<dim3(64, 4, 3), 512, 0, stream>>>(xb, Wb, Qb, Kb, VTb, 0);
        sp_old<<<dim3(8, 8, 8), 512, 0, stream>>>(Qb, Kb, Pb);
        pv_old<<<dim3(64, 4), 512, 0, stream>>>(Pb, VTb, Of);
        finalize<<<dim3(16384), 256, 0, stream>>>(Pb, Of, (float*)d_out);
    }
}

// Round 11
// 254.617 us; speedup vs baseline: 1.0536x; 1.0536x over previous
//
#include <hip/hip_runtime.h>

typedef unsigned short u16;
typedef short short8 __attribute__((ext_vector_type(8)));
typedef float f32x4 __attribute__((ext_vector_type(4)));
typedef unsigned long long u64;

// ---- r8 ws layout (fallback tier 1) ----
#define WS_K_OFF    33554432ULL
#define WS_PTRI     67108864ULL
#define WS_PART     104857600ULL
#define WS_NEED     105447424ULL
// ---- new layout (tier 0): Q | K | VT | Ptri | part ----
#define W2_K        33554432ULL
#define W2_VT       67108864ULL
#define W2_PTRI     100663296ULL
#define W2_PART     138412032ULL
#define W2_NEED     139001856ULL

__device__ __forceinline__ u16 f2bf(float f) {
    union { float f; unsigned u; } c; c.f = f;
    unsigned r = c.u + 0x7fffu + ((c.u >> 16) & 1u);
    return (u16)(r >> 16);
}
__device__ __forceinline__ float bf2f(u16 h) {
    union { unsigned u; float f; } c; c.u = ((unsigned)h) << 16; return c.f;
}
__device__ __forceinline__ void gll16(const u16* g, u16* l) {
    __builtin_amdgcn_global_load_lds(
        (const __attribute__((address_space(1))) void*)g,
        (__attribute__((address_space(3))) void*)l, 16, 0, 0);
}

// ---------------------------------------------------------------------------
// r7/r8 deep-pipe 256x256 NT-GEMM mainloop (best-measured; frozen).
// ---------------------------------------------------------------------------
template<int AMODE>
__device__ __forceinline__ void gemm_pipe(
    const u16* __restrict__ A, int lda,
    const u16* __restrict__ B, int ldb,
    int m0, int n0, int nk, u16* lds, f32x4 acc[8][4])
{
    const int tid  = threadIdx.x;
    const int lane = tid & 63;
    const int w    = tid >> 6;
    const int wm   = w >> 2, wn = w & 3;
    const int kg   = lane >> 4, l15 = lane & 15;
    const int r0   = w * 32 + (lane >> 2);
    const int s0   = (lane & 3) ^ ((r0 >> 1) & 3);

    const int ldA = AMODE ? 256 : lda;
    const u16* Ar0 = A + (size_t)(m0 + r0) * ldA + s0 * 8;
    const u16* Ar1 = Ar0 + 16 * ldA;
    const u16* Br0 = B + (size_t)(n0 + r0) * ldb + s0 * 8;
    const u16* Br1 = Br0 + 16 * ldb;

    auto aoff = [&](int t) -> int {
        return AMODE ? ((t >> 3) * 65536 + (t & 7) * 32) : t * 32;
    };
    auto STAGE = [&](int t) {
        const int ao = aoff(t), bo = t * 32, buf = (t & 3) * 16384;
        u16* dA = lds + buf + w * 1024;
        u16* dB = lds + buf + 8192 + w * 1024;
        gll16(Ar0 + ao, dA);
        gll16(Ar1 + ao, dA + 512);
        gll16(Br0 + bo, dB);
        gll16(Br1 + bo, dB + 512);
    };
    auto LDA8 = [&](short8* fa, int t) {
        const u16* h = lds + (t & 3) * 16384 + wm * 4096;
        #pragma unroll
        for (int mt = 0; mt < 8; ++mt) {
            const int row = mt * 16 + l15;
            fa[mt] = *reinterpret_cast<const short8*>(
                h + row * 32 + ((kg ^ ((row >> 1) & 3)) << 3));
        }
    };
    auto LDB4 = [&](short8* fb, int t) {
        const u16* h = lds + (t & 3) * 16384 + 8192 + wn * 2048;
        #pragma unroll
        for (int nt = 0; nt < 4; ++nt) {
            const int row = nt * 16 + l15;
            fb[nt] = *reinterpret_cast<const short8*>(
                h + row * 32 + ((kg ^ ((row >> 1) & 3)) << 3));
        }
    };
    auto MFMA32 = [&](short8* fa, short8* fb) {
        __builtin_amdgcn_s_setprio(1);
        #pragma unroll
        for (int mt = 0; mt < 8; ++mt)
            #pragma unroll
            for (int nt = 0; nt < 4; ++nt)
                acc[mt][nt] = __builtin_amdgcn_mfma_f32_16x16x32_bf16(
                    fa[mt], fb[nt], acc[mt][nt], 0, 0, 0);
        __builtin_amdgcn_s_setprio(0);
    };

    STAGE(0); STAGE(1); STAGE(2);
    asm volatile("s_waitcnt vmcnt(4)" ::: "memory");
    __builtin_amdgcn_s_barrier();

    short8 faA[8], faB[8], fb[4];
    LDA8(faA, 0);

    for (int t = 0; t < nk; t += 2) {
        LDB4(fb, t);
        LDA8(faB, t + 1);
        if (t + 3 < nk) STAGE(t + 3);
        MFMA32(faA, fb);
        if (t + 3 < nk) asm volatile("s_waitcnt vmcnt(4)" ::: "memory");
        else            asm volatile("s_waitcnt vmcnt(0)" ::: "memory");
        __builtin_amdgcn_s_barrier();

        LDB4(fb, t + 1);
        if (t + 2 < nk) LDA8(faA, t + 2);
        if (t + 4 < nk) STAGE(t + 4);
        MFMA32(faB, fb);
        if (t + 4 < nk) asm volatile("s_waitcnt vmcnt(4)" ::: "memory");
        else            asm volatile("s_waitcnt vmcnt(0)" ::: "memory");
        __builtin_amdgcn_s_barrier();
    }
}

// ---------------------------------------------------------------------------
// 0) cast x and Wq/Wk/Wv to bf16 into d_out: xb[16M] then Wb[3][1M]
// ---------------------------------------------------------------------------
__global__ __launch_bounds__(256) void cvt_bf16(
    const float* __restrict__ x,
    const float* __restrict__ Wq,
    const float* __restrict__ Wk,
    const float* __restrict__ Wv,
    u16* __restrict__ dst)
{
    const size_t e = ((size_t)blockIdx.x * 256 + threadIdx.x) * 8;
    const float* src;
    if (e < (size_t)16777216) {
        src = x + e;
    } else {
        size_t j = e - 16777216;
        int z = (int)(j >> 20);
        const float* Wz = (z == 0) ? Wq : (z == 1) ? Wk : Wv;
        src = Wz + (j & 1048575);
    }
    float4 a = *reinterpret_cast<const float4*>(src);
    float4 b = *reinterpret_cast<const float4*>(src + 4);
    short8 v;
    v[0] = (short)f2bf(a.x); v[1] = (short)f2bf(a.y);
    v[2] = (short)f2bf(a.z); v[3] = (short)f2bf(a.w);
    v[4] = (short)f2bf(b.x); v[5] = (short)f2bf(b.y);
    v[6] = (short)f2bf(b.z); v[7] = (short)f2bf(b.w);
    *reinterpret_cast<short8*>(dst + e) = v;
}

// ---------------------------------------------------------------------------
// 1) projection. z = blockIdx.z + zbase: 0 -> Q, 1 -> K, 2 -> V^T[b][h][t].
// z==2 now uses an LDS-transposed COALESCED epilogue (two 128-h halves;
// packed 8B ds_writes into [128][264]; 16B/lane contiguous global stores)
// instead of the 2-byte scatter (which made a z2 round 2x a z01 round).
// ---------------------------------------------------------------------------
__global__ __launch_bounds__(512, 2) void qkv_pipe(
    const u16* __restrict__ xb, const u16* __restrict__ Wb,
    u16* __restrict__ Qo, u16* __restrict__ Ko, u16* __restrict__ VTo, int zbase)
{
    __shared__ u16 L[65536];
    const int tid = threadIdx.x, lane = tid & 63, w = tid >> 6;
    const int wm = w >> 2, wn = w & 3, kg = lane >> 4, l15 = lane & 15;
    const int m0 = blockIdx.x * 256, n0 = blockIdx.y * 256;
    const int z = blockIdx.z + zbase;

    const f32x4 z4 = {0.f, 0.f, 0.f, 0.f};
    f32x4 acc[8][4];
    #pragma unroll
    for (int i = 0; i < 8; ++i)
        #pragma unroll
        for (int j = 0; j < 4; ++j) acc[i][j] = z4;

    gemm_pipe<0>(xb, 1024, Wb + (size_t)z * 1048576, 1024, m0, n0, 32, L, acc);
    // mainloop ends vmcnt(0)+barrier: LDS quiescent

    if (z < 2) {
        u16* O = (z == 0) ? Qo : Ko;
        #pragma unroll
        for (int mt = 0; mt < 8; ++mt) {
            const int row0 = m0 + wm * 128 + mt * 16 + kg * 4;
            #pragma unroll
            for (int nt = 0; nt < 4; ++nt) {
                const int col = n0 + wn * 64 + nt * 16 + l15;
                #pragma unroll
                for (int r = 0; r < 4; ++r)
                    O[(size_t)(row0 + r) * 1024 + col] = f2bf(acc[mt][nt][r]);
            }
        }
    } else {
        const int b    = m0 >> 11;
        const int mloc = m0 & 2047;
        const int t8   = (tid & 31) * 8;
        const int hh   = tid >> 5;          // 0..15
        #pragma unroll
        for (int half = 0; half < 2; ++half) {
            if ((wn >> 1) == half) {        // 4 producing waves per half
                const int hb = (wn & 1) * 64;
                #pragma unroll
                for (int mt = 0; mt < 8; ++mt) {
                    const int tl = wm * 128 + mt * 16 + kg * 4;  // 8B-aligned
                    #pragma unroll
                    for (int nt = 0; nt < 4; ++nt) {
                        const int hl = hb + nt * 16 + l15;
                        u64 pk = (u64)f2bf(acc[mt][nt][0])
                               | ((u64)f2bf(acc[mt][nt][1]) << 16)
                               | ((u64)f2bf(acc[mt][nt][2]) << 32)
                               | ((u64)f2bf(acc[mt][nt][3]) << 48);
                        *reinterpret_cast<u64*>(&L[hl * 264 + tl]) = pk;
                    }
                }
            }
            __syncthreads();
            #pragma unroll
            for (int p = 0; p < 8; ++p) {
                const int hl = p * 16 + hh;
                short8 v = *reinterpret_cast<const short8*>(&L[hl * 264 + t8]);
                *reinterpret_cast<short8*>(
                    &VTo[((size_t)b * 1024 + n0 + half * 128 + hl) * 2048 + mloc + t8]) = v;
            }
            __syncthreads();                // before half 1 overwrites LDS
        }
    }
}

// ---------------------------------------------------------------------------
// Shared triple-buffer 256x128 NT-GEMM body (unchanged from r8).
// ---------------------------------------------------------------------------
template<int AMODE>
__device__ __forceinline__ void gemm_tri128(
    const u16* __restrict__ A, int lda,
    const u16* __restrict__ B, int ldb, int nk, u16* L, f32x4 acc[4][4])
{
    const int tid = threadIdx.x, lane = tid & 63, w = tid >> 6;
    const int wm = w >> 1, wn = w & 1, kg = lane >> 4, l15 = lane & 15;

    const int rA = w * 32 + (lane >> 2);
    const int sA = (lane & 3) ^ ((rA >> 1) & 3);
    const int rB = w * 16 + (lane >> 2);
    const int sB = (lane & 3) ^ ((rB >> 1) & 3);
    const int ldA = AMODE ? 256 : lda;
    const u16* Ar0 = A + (size_t)rA * ldA + sA * 8;
    const u16* Ar1 = Ar0 + 16 * ldA;
    const u16* Br0 = B + (size_t)rB * ldb + sB * 8;

    auto aoff = [&](int t) -> int {
        return AMODE ? ((t >> 3) * 65536 + (t & 7) * 32) : t * 32;
    };
    auto STAGE = [&](int t) {
        u16* d = L + (t % 3) * 12288;
        gll16(Ar0 + aoff(t), d + w * 1024);
        gll16(Ar1 + aoff(t), d + w * 1024 + 512);
        gll16(Br0 + t * 32,  d + 8192 + w * 512);
    };
    auto LDA4 = [&](short8* fa, int t) {
        const u16* h = L + (t % 3) * 12288;
        #pragma unroll
        for (int mt = 0; mt < 4; ++mt) {
            const int row = wm * 64 + mt * 16 + l15;
            fa[mt] = *reinterpret_cast<const short8*>(
                h + row * 32 + ((kg ^ ((row >> 1) & 3)) << 3));
        }
    };
    auto LDB4 = [&](short8* fb, int t) {
        const u16* h = L + (t % 3) * 12288 + 8192;
        #pragma unroll
        for (int nt = 0; nt < 4; ++nt) {
            const int row = wn * 64 + nt * 16 + l15;
            fb[nt] = *reinterpret_cast<const short8*>(
                h + row * 32 + ((kg ^ ((row >> 1) & 3)) << 3));
        }
    };

    STAGE(0); STAGE(1);
    asm volatile("s_waitcnt vmcnt(3)" ::: "memory");   // tile 0 landed
    __builtin_amdgcn_s_barrier();

    short8 fa[4], fb[4];
    for (int t = 0; t < nk; ++t) {
        LDA4(fa, t);
        LDB4(fb, t);
        if (t + 2 < nk) STAGE(t + 2);
        __builtin_amdgcn_s_setprio(1);
        #pragma unroll
        for (int mt = 0; mt < 4; ++mt)
            #pragma unroll
            for (int nt = 0; nt < 4; ++nt)
                acc[mt][nt] = __builtin_amdgcn_mfma_f32_16x16x32_bf16(
                    fa[mt], fb[nt], acc[mt][nt], 0, 0, 0);
        __builtin_amdgcn_s_setprio(0);
        if (t + 2 < nk) asm volatile("s_waitcnt vmcnt(3)" ::: "memory");
        else            asm volatile("s_waitcnt vmcnt(0)" ::: "memory");
        __builtin_amdgcn_s_barrier();
    }
}

// ---------------------------------------------------------------------------
// 2a) sp128 (unchanged from r8)
// ---------------------------------------------------------------------------
__global__ __launch_bounds__(512, 4) void sp128(
    const u16* __restrict__ Q, const u16* __restrict__ K,
    u16* __restrict__ Ptri, float* __restrict__ part)
{
    __shared__ u16 L[36864];
    int jj = blockIdx.x;
    const int b = jj / 72;
    int r = jj - b * 72;
    int qb = 0;
    while (r >= 2 * qb + 2) { r -= 2 * qb + 2; ++qb; }
    const int kb = r;

    const int tid = threadIdx.x, lane = tid & 63, w = tid >> 6;
    const int wm = w >> 1, wn = w & 1, kg = lane >> 4, l15 = lane & 15;

    const f32x4 z4 = {0.f, 0.f, 0.f, 0.f};
    f32x4 acc[4][4];
    #pragma unroll
    for (int a_ = 0; a_ < 4; ++a_)
        #pragma unroll
        for (int j = 0; j < 4; ++j) acc[a_][j] = z4;

    gemm_tri128<0>(Q + (size_t)(b * 2048 + qb * 256) * 1024, 1024,
                   K + (size_t)(b * 2048 + kb * 128) * 1024, 1024,
                   32, L, acc);

    u16* Pt = Ptri + ((size_t)b * 36 + (qb * (qb + 1)) / 2 + (kb >> 1)) * 65536
                   + (kb & 1) * 128;
    float* psum = (float*)L;
    #pragma unroll
    for (int mt = 0; mt < 4; ++mt) {
        #pragma unroll
        for (int rr = 0; rr < 4; ++rr) {
            const int lt = wm * 64 + mt * 16 + kg * 4 + rr;
            const int gt = qb * 256 + lt;
            float ps = 0.f;
            #pragma unroll
            for (int nt = 0; nt < 4; ++nt) {
                const int lcol = wn * 64 + nt * 16 + l15;
                const int gs = kb * 128 + lcol;
                const float p = (gs <= gt) ? __expf(acc[mt][nt][rr] * 0.03125f) : 0.f;
                ps += p;
                Pt[(size_t)lt * 256 + lcol] = f2bf(p);
            }
            #pragma unroll
            for (int d = 1; d < 16; d <<= 1) ps += __shfl_xor(ps, d, 64);
            if (l15 == 0) psum[lt * 2 + wn] = ps;
        }
    }
    __syncthreads();
    if (tid < 256) {
        const float s = psum[tid * 2] + psum[tid * 2 + 1];
        part[(size_t)b * 18432 + (qb * qb + qb) * 256 + tid * (2 * qb + 2) + kb] = s;
    }
}

// 2b) OLD: full-square P in d_out (fallback tier 2)
__global__ __launch_bounds__(512, 2) void sp_old(
    const u16* __restrict__ Q, const u16* __restrict__ K, u16* __restrict__ P)
{
    const int qb = blockIdx.x, kb = blockIdx.y, b = blockIdx.z;
    if (kb > qb) return;
    __shared__ u16 L[65536];
    const int tid = threadIdx.x, lane = tid & 63, w = tid >> 6;
    const int wm = w >> 2, wn = w & 3, kg = lane >> 4, l15 = lane & 15;

    const f32x4 z4 = {0.f, 0.f, 0.f, 0.f};
    f32x4 acc[8][4];
    #pragma unroll
    for (int i = 0; i < 8; ++i)
        #pragma unroll
        for (int j = 0; j < 4; ++j) acc[i][j] = z4;

    gemm_pipe<0>(Q, 1024, K, 1024, b * 2048 + qb * 256, b * 2048 + kb * 256, 32, L, acc);

    u16* Pb = P + (size_t)b * 2048 * 2048;
    #pragma unroll
    for (int mt = 0; mt < 8; ++mt) {
        const int trow0 = qb * 256 + wm * 128 + mt * 16 + kg * 4;
        #pragma unroll
        for (int nt = 0; nt < 4; ++nt) {
            const int scol = kb * 256 + wn * 64 + nt * 16 + l15;
            #pragma unroll
            for (int r = 0; r < 4; ++r) {
                const int trow = trow0 + r;
                const float p = (scol <= trow) ? __expf(acc[mt][nt][r] * 0.03125f) : 0.f;
                Pb[(size_t)trow * 2048 + scol] = f2bf(p);
            }
        }
    }
}

// ---------------------------------------------------------------------------
// 4a) pv128 (unchanged from r8)
// ---------------------------------------------------------------------------
__global__ __launch_bounds__(512, 4) void pv128(
    const u16* __restrict__ Ptri, const u16* __restrict__ VT,
    const float* __restrict__ part, float* __restrict__ out)
{
    __shared__ u16 L[36864];
    const int i = blockIdx.x;
    const int c = i >> 7;
    const int j = (i >> 1) & 63;
    const int s = i & 1;
    const int q  = s ? c : 7 - c;
    const int b  = j >> 3;
    const int nb = j & 7;
    const int nk = (q + 1) * 8;

    const int tid = threadIdx.x, lane = tid & 63, w = tid >> 6;
    const int wm = w >> 1, wn = w & 1, kg = lane >> 4, l15 = lane & 15;

    const f32x4 z4 = {0.f, 0.f, 0.f, 0.f};
    f32x4 acc[4][4];
    #pragma unroll
    for (int a_ = 0; a_ < 4; ++a_)
        #pragma unroll
        for (int jx = 0; jx < 4; ++jx) acc[a_][jx] = z4;

    gemm_tri128<1>(Ptri + ((size_t)b * 36 + (q * (q + 1)) / 2) * 65536, 256,
                   VT + ((size_t)b * 1024 + nb * 128) * 2048, 2048,
                   nk, L, acc);

    float* Lf = (float*)L;
    if (tid < 256) {
        const int nkb = 2 * q + 2;
        const float* pp = part + (size_t)b * 18432 + (q * q + q) * 256 + tid * nkb;
        float sum = 0.f;
        for (int kb = 0; kb < nkb; ++kb) sum += pp[kb];
        Lf[tid] = 1.f / sum;
    }
    __syncthreads();

    #pragma unroll
    for (int mt = 0; mt < 4; ++mt) {
        const int lt0 = wm * 64 + mt * 16 + kg * 4;
        const size_t grow0 = (size_t)b * 2048 + q * 256 + lt0;
        float rs[4];
        #pragma unroll
        for (int r = 0; r < 4; ++r) rs[r] = Lf[lt0 + r];
        #pragma unroll
        for (int nt = 0; nt < 4; ++nt) {
            const int col = nb * 128 + wn * 64 + nt * 16 + l15;
            #pragma unroll
            for (int r = 0; r < 4; ++r)
                out[(grow0 + r) * 1024 + col] = acc[mt][nt][r] * rs[r];
        }
    }
}

// 4b) OLD: O = P * V^T (unnormalized f32) -> Of in ws (fallback tier 2)
__global__ __launch_bounds__(512, 2) void pv_old(
    const u16* __restrict__ P, const u16* __restrict__ VT, float* __restrict__ Of)
{
    const int b = blockIdx.x >> 3, qblk = blockIdx.x & 7;
    const int nb = blockIdx.y;
    const int nk = (qblk + 1) * 8;
    __shared__ u16 L[65536];
    const int tid = threadIdx.x, lane = tid & 63, w = tid >> 6;
    const int wm = w >> 2, wn = w & 3, kg = lane >> 4, l15 = lane & 15;

    const f32x4 z4 = {0.f, 0.f, 0.f, 0.f};
    f32x4 acc[8][4];
    #pragma unroll
    for (int i = 0; i < 8; ++i)
        #pragma unroll
        for (int j = 0; j < 4; ++j) acc[i][j] = z4;

    gemm_pipe<0>(P + (size_t)b * 2048 * 2048, 2048,
                 VT + (size_t)b * 1024 * 2048, 2048,
                 qblk * 256, nb * 256, nk, L, acc);

    #pragma unroll
    for (int mt = 0; mt < 8; ++mt) {
        const int trow0 = qblk * 256 + wm * 128 + mt * 16 + kg * 4;
        #pragma unroll
        for (int nt = 0; nt < 4; ++nt) {
            const int col = nb * 256 + wn * 64 + nt * 16 + l15;
            #pragma unroll
            for (int r = 0; r < 4; ++r)
                Of[((size_t)b * 2048 + trow0 + r) * 1024 + col] = acc[mt][nt][r];
        }
    }
}

// 5) OLD: per row l = sum(P row); out = Of / l (fallback tier 2)
__global__ __launch_bounds__(256) void finalize(
    const u16* __restrict__ P, const float* __restrict__ Of, float* __restrict__ out)
{
    const int row = blockIdx.x;
    const int tid = threadIdx.x;
    const int b = row >> 11, t = row & 2047;
    const int len = ((t >> 8) + 1) * 256;
    const u16* prow = P + ((size_t)b * 2048 + t) * 2048;

    float s = 0.f;
    const int i = tid * 8;
    if (i < len) {
        short8 v = *reinterpret_cast<const short8*>(prow + i);
        #pragma unroll
        for (int j = 0; j < 8; ++j) s += bf2f((u16)v[j]);
    }
    #pragma unroll
    for (int d = 1; d < 64; d <<= 1) s += __shfl_xor(s, d, 64);

    __shared__ float red[4];
    if ((tid & 63) == 0) red[tid >> 6] = s;
    __syncthreads();
    const float rinv = 1.f / (red[0] + red[1] + red[2] + red[3]);

    const size_t o = (size_t)row * 1024 + tid * 4;
    f32x4 v = *reinterpret_cast<const f32x4*>(Of + o);
    v[0] *= rinv; v[1] *= rinv; v[2] *= rinv; v[3] *= rinv;
    *reinterpret_cast<f32x4*>(out + o) = v;
}

extern "C" void kernel_launch(void* const* d_in, const int* in_sizes, int n_in,
                              void* d_out, int out_size, void* d_ws, size_t ws_size,
                              hipStream_t stream) {
    const float* x  = (const float*)d_in[0];
    const float* Wq = (const float*)d_in[1];
    const float* Wk = (const float*)d_in[2];
    const float* Wv = (const float*)d_in[3];

    // d_out overlays: phase A = xb[16M]+Wb[3M] bf16; final = out f32
    u16* xb = (u16*)d_out;
    u16* Wb = xb + (size_t)16777216;

    cvt_bf16<<<dim3(9728), 256, 0, stream>>>(x, Wq, Wk, Wv, xb);

    if (ws_size >= W2_NEED) {
        // TIER 0: ws = Q | K | VT | Ptri | part — no aliasing, ONE qkv launch
        u16*   Qb   = (u16*)d_ws;
        u16*   Kb   = (u16*)((char*)d_ws + W2_K);
        u16*   VTb  = (u16*)((char*)d_ws + W2_VT);
        u16*   Pt   = (u16*)((char*)d_ws + W2_PTRI);
        float* part = (float*)((char*)d_ws + W2_PART);

        qkv_pipe<<<dim3(64, 4, 3), 512, 0, stream>>>(xb, Wb, Qb, Kb, VTb, 0);
        sp128<<<dim3(576), 512, 0, stream>>>(Qb, Kb, Pt, part);
        pv128<<<dim3(512), 512, 0, stream>>>(Pt, VTb, part, (float*)d_out);
    } else if (ws_size >= WS_NEED) {
        // TIER 1 (r8 path): ws = Q | K | Ptri | part ; VT overwrites Q after sp
        u16*   Qb   = (u16*)d_ws;
        u16*   Kb   = (u16*)((char*)d_ws + WS_K_OFF);
        u16*   Pt   = (u16*)((char*)d_ws + WS_PTRI);
        float* part = (float*)((char*)d_ws + WS_PART);
        u16*   VTb  = Qb;   // Q dead after sp128

        qkv_pipe<<<dim3(64, 4, 2), 512, 0, stream>>>(xb, Wb, Qb, Kb, Qb, 0);
        sp128<<<dim3(576), 512, 0, stream>>>(Qb, Kb, Pt, part);
        qkv_pipe<<<dim3(64, 4, 1), 512, 0, stream>>>(xb, Wb, Qb, Kb, VTb, 2);
        pv128<<<dim3(512), 512, 0, stream>>>(Pt, VTb, part, (float*)d_out);
    } else {
        // TIER 2 (r3 dataflow): ws = Q | K | VT ; P in d_out; Of over Q/K
        u16* Qb  = (u16*)d_ws;
        u16* Kb  = Qb + (size_t)16384 * 1024;
        u16* VTb = Kb + (size_t)16384 * 1024;
        float* Of = (float*)d_ws;
        u16* Pb = (u16*)d_out;

        qkv_pipe<<<dim3(64, 4, 3), 512, 0, stream>>>(xb, Wb, Qb, Kb, VTb, 0);
        sp_old<<<dim3(8, 8, 8), 512, 0, stream>>>(Qb, Kb, Pb);
        pv_old<<<dim3(64, 4), 512, 0, stream>>>(Pb, VTb, Of);
        finalize<<<dim3(16384), 256, 0, stream>>>(Pb, Of, (float*)d_out);
    }
}